// Round 1
// baseline (1626.350 us; speedup 1.0000x reference)
//
#include <hip/hip_runtime.h>
#include <hip/hip_bf16.h>

// ---------------------------------------------------------------------------
// SparseKnowledgeAttention: q=ego@Wq.T+bq; k=(side*rel)@Wk.T+bk; v=side@Wv.T+bv
// scores=q@k.T/16 -> top16/row -> softmax -> weighted gather of v.
// Strategy: fp16x3 split-precision MFMA (f32-equivalent scores so top-k
// selection matches the f32 numpy reference), fused score+top16 kernel with
// per-row running lists, then a merge/softmax/gather kernel.
// ---------------------------------------------------------------------------

#define EMB 256
#define NEGO 8192
#define NSIDE 8192
#define TOPKK 16
#define NSPLIT 4
#define SPLITLEN (NSIDE / NSPLIT)   // 2048
#define BM 128                      // ego rows per block (4 waves x 32)
#define BN 64                       // side cols per iteration

typedef _Float16 f16x8 __attribute__((ext_vector_type(8)));
typedef float f32x16 __attribute__((ext_vector_type(16)));

#define NEG_BIG (-3.402823466e38f)

__device__ __forceinline__ void gload_lds16(const _Float16* g, _Float16* l) {
    __builtin_amdgcn_global_load_lds((const __attribute__((address_space(1))) void*)g,
                                     (__attribute__((address_space(3))) void*)l, 16, 0, 0);
}

__device__ __forceinline__ void split8(const float* xv, f16x8& hi, f16x8& lo) {
#pragma unroll
    for (int j = 0; j < 8; ++j) {
        float x = xv[j];
        _Float16 h = (_Float16)x;
        hi[j] = h;
        lo[j] = (_Float16)(x - (float)h);
    }
}

// ---------------------------------------------------------------------------
// Projection kernel: C = X @ W.T + b  via fp16x3 MFMA. z = 0:q, 1:k, 2:v.
// grid (64, 3), block 256. Outputs: q,k as f16 hi/lo pairs; v as f32.
// ---------------------------------------------------------------------------
__global__ __launch_bounds__(256, 1) void proj_kernel(
    const float* __restrict__ ego, const float* __restrict__ side, const float* __restrict__ rel,
    const float* __restrict__ Wq, const float* __restrict__ bq,
    const float* __restrict__ Wk, const float* __restrict__ bk,
    const float* __restrict__ Wv, const float* __restrict__ bv,
    _Float16* __restrict__ qh, _Float16* __restrict__ ql,
    _Float16* __restrict__ kh, _Float16* __restrict__ kl,
    float* __restrict__ vout)
{
    __shared__ __align__(16) _Float16 Wh[64 * 256];   // 32KB, chunk-swizzled
    __shared__ __align__(16) _Float16 Wl[64 * 256];   // 32KB

    const int z = blockIdx.y;
    const float* X; const float* W; const float* bias;
    if (z == 0)      { X = ego;  W = Wq; bias = bq; }
    else if (z == 1) { X = side; W = Wk; bias = bk; }
    else             { X = side; W = Wv; bias = bv; }

    const int tid = threadIdx.x, lane = tid & 63, wave = tid >> 6;
    const int hk = lane >> 5, r = lane & 31;
    const int arow = blockIdx.x * BM + wave * 32 + r;

    // A fragments (rows of X), fp16 split, held in registers for whole block.
    f16x8 ah[16], al[16];
#pragma unroll
    for (int kst = 0; kst < 16; ++kst) {
        float xv[8];
        const float* p = X + arow * EMB + kst * 16 + hk * 8;
        const float4 x0 = *(const float4*)p;
        const float4 x1 = *(const float4*)(p + 4);
        xv[0]=x0.x; xv[1]=x0.y; xv[2]=x0.z; xv[3]=x0.w;
        xv[4]=x1.x; xv[5]=x1.y; xv[6]=x1.z; xv[7]=x1.w;
        if (z == 1) {
            const float* pr = rel + arow * EMB + kst * 16 + hk * 8;
            const float4 r0 = *(const float4*)pr;
            const float4 r1 = *(const float4*)(pr + 4);
            xv[0]*=r0.x; xv[1]*=r0.y; xv[2]*=r0.z; xv[3]*=r0.w;
            xv[4]*=r1.x; xv[5]*=r1.y; xv[6]*=r1.z; xv[7]*=r1.w;
        }
        split8(xv, ah[kst], al[kst]);
    }

    for (int nt = 0; nt < 4; ++nt) {
        __syncthreads();
        // Stage W rows [nt*64, nt*64+64) into LDS, split + chunk-swizzled.
#pragma unroll
        for (int i = 0; i < 8; ++i) {
            const int rowi = wave * 16 + i * 2 + hk;
            const int c = r;
            const float* wp = W + (nt * 64 + rowi) * EMB + ((c ^ (rowi & 31)) << 3);
            float xv[8];
            const float4 w0 = *(const float4*)wp;
            const float4 w1 = *(const float4*)(wp + 4);
            xv[0]=w0.x; xv[1]=w0.y; xv[2]=w0.z; xv[3]=w0.w;
            xv[4]=w1.x; xv[5]=w1.y; xv[6]=w1.z; xv[7]=w1.w;
            f16x8 h8, l8;
            split8(xv, h8, l8);
            *(f16x8*)&Wh[rowi * 256 + c * 8] = h8;
            *(f16x8*)&Wl[rowi * 256 + c * 8] = l8;
        }
        __syncthreads();

        f32x16 acc0 = {}, acc1 = {};
#pragma unroll
        for (int kst = 0; kst < 16; ++kst) {
            const int cc = kst * 2 + hk;
            const f16x8 bh0 = *(const f16x8*)&Wh[r * 256 + ((cc ^ r) << 3)];
            const f16x8 bl0 = *(const f16x8*)&Wl[r * 256 + ((cc ^ r) << 3)];
            const f16x8 bh1 = *(const f16x8*)&Wh[(32 + r) * 256 + ((cc ^ r) << 3)];
            const f16x8 bl1 = *(const f16x8*)&Wl[(32 + r) * 256 + ((cc ^ r) << 3)];
            acc0 = __builtin_amdgcn_mfma_f32_32x32x16_f16(ah[kst], bh0, acc0, 0, 0, 0);
            acc0 = __builtin_amdgcn_mfma_f32_32x32x16_f16(al[kst], bh0, acc0, 0, 0, 0);
            acc0 = __builtin_amdgcn_mfma_f32_32x32x16_f16(ah[kst], bl0, acc0, 0, 0, 0);
            acc1 = __builtin_amdgcn_mfma_f32_32x32x16_f16(ah[kst], bh1, acc1, 0, 0, 0);
            acc1 = __builtin_amdgcn_mfma_f32_32x32x16_f16(al[kst], bh1, acc1, 0, 0, 0);
            acc1 = __builtin_amdgcn_mfma_f32_32x32x16_f16(ah[kst], bl1, acc1, 0, 0, 0);
        }

        // Epilogue: add bias, write (split f16 for q/k; f32 for v).
#pragma unroll
        for (int reg = 0; reg < 16; ++reg) {
            const int crow = (reg & 3) + 8 * (reg >> 2) + 4 * hk;
            const int grow = blockIdx.x * BM + wave * 32 + crow;
            const int col0 = nt * 64 + r;
            const int col1 = nt * 64 + 32 + r;
            const float v0 = acc0[reg] + bias[col0];
            const float v1 = acc1[reg] + bias[col1];
            if (z < 2) {
                _Float16* oh = (z == 0) ? qh : kh;
                _Float16* ol = (z == 0) ? ql : kl;
                _Float16 h0 = (_Float16)v0;
                oh[grow * EMB + col0] = h0;
                ol[grow * EMB + col0] = (_Float16)(v0 - (float)h0);
                _Float16 h1 = (_Float16)v1;
                oh[grow * EMB + col1] = h1;
                ol[grow * EMB + col1] = (_Float16)(v1 - (float)h1);
            } else {
                vout[grow * EMB + col0] = v0;
                vout[grow * EMB + col1] = v1;
            }
        }
    }
}

// ---------------------------------------------------------------------------
// Fused scores + running top-16. grid (64, NSPLIT), block 256 (4 waves x 32 rows).
// Each block: 128 ego rows vs a 2048-row side slice; emits partial top-16.
// ---------------------------------------------------------------------------
__global__ __launch_bounds__(256, 1) void scores_topk_kernel(
    const _Float16* __restrict__ qh, const _Float16* __restrict__ ql,
    const _Float16* __restrict__ kh, const _Float16* __restrict__ kl,
    float* __restrict__ part_sc, int* __restrict__ part_id)
{
    __shared__ __align__(16) _Float16 Bh[BN * 256];   // 32KB swizzled k-tile (hi)
    __shared__ __align__(16) _Float16 Bl[BN * 256];   // 32KB (lo)
    __shared__ float sbuf[4][32 * 65];                // per-wave score tile, +1 pad
    __shared__ float tk_sc[BM * 17];                  // stride 17: conflict-free rescan
    __shared__ int   tk_id[BM * 17];

    const int tid = threadIdx.x, lane = tid & 63, wave = tid >> 6;
    const int hk = lane >> 5, r = lane & 31;
    const int split = blockIdx.y;

    for (int i = tid; i < BM * 17; i += 256) { tk_sc[i] = NEG_BIG; tk_id[i] = 0x7fffffff; }

    // Q fragments in registers for the whole side loop.
    const int qrow = blockIdx.x * BM + wave * 32 + r;
    f16x8 ah[16], al[16];
#pragma unroll
    for (int kst = 0; kst < 16; ++kst) {
        ah[kst] = *(const f16x8*)(qh + qrow * EMB + kst * 16 + hk * 8);
        al[kst] = *(const f16x8*)(ql + qrow * EMB + kst * 16 + hk * 8);
    }

    float thr = NEG_BIG; int thr_id = 0x7fffffff, minslot = 0;
    const int lbase = (wave * 32 + r) * 17;

    for (int it = 0; it < SPLITLEN / BN; ++it) {
        const int s0 = split * SPLITLEN + it * BN;
        __syncthreads();   // previous iteration done reading B
        // Stage k-tile hi/lo via global_load_lds; source pre-swizzled so the
        // linear LDS dest realizes chunk ^= (row&31) -> conflict-free ds_read_b128.
#pragma unroll
        for (int i = 0; i < 8; ++i) {
            const int rowi = wave * 16 + i * 2 + hk;
            const int c = r;
            const int gsrc = (s0 + rowi) * EMB + ((c ^ (rowi & 31)) << 3);
            gload_lds16(kh + gsrc, &Bh[(wave * 16 + i * 2) * 256]);
            gload_lds16(kl + gsrc, &Bl[(wave * 16 + i * 2) * 256]);
        }
        __syncthreads();   // staged (compiler drains vmcnt)

        f32x16 acc0 = {}, acc1 = {};
#pragma unroll
        for (int kst = 0; kst < 16; ++kst) {
            const int cc = kst * 2 + hk;
            const f16x8 bh0 = *(const f16x8*)&Bh[r * 256 + ((cc ^ r) << 3)];
            const f16x8 bl0 = *(const f16x8*)&Bl[r * 256 + ((cc ^ r) << 3)];
            const f16x8 bh1 = *(const f16x8*)&Bh[(32 + r) * 256 + ((cc ^ r) << 3)];
            const f16x8 bl1 = *(const f16x8*)&Bl[(32 + r) * 256 + ((cc ^ r) << 3)];
            acc0 = __builtin_amdgcn_mfma_f32_32x32x16_f16(ah[kst], bh0, acc0, 0, 0, 0);
            acc0 = __builtin_amdgcn_mfma_f32_32x32x16_f16(al[kst], bh0, acc0, 0, 0, 0);
            acc0 = __builtin_amdgcn_mfma_f32_32x32x16_f16(ah[kst], bl0, acc0, 0, 0, 0);
            acc1 = __builtin_amdgcn_mfma_f32_32x32x16_f16(ah[kst], bh1, acc1, 0, 0, 0);
            acc1 = __builtin_amdgcn_mfma_f32_32x32x16_f16(al[kst], bh1, acc1, 0, 0, 0);
            acc1 = __builtin_amdgcn_mfma_f32_32x32x16_f16(ah[kst], bl1, acc1, 0, 0, 0);
        }

        // Scores (scaled by 1/sqrt(256)) -> per-wave LDS tile.
        float* sb = sbuf[wave];
#pragma unroll
        for (int reg = 0; reg < 16; ++reg) {
            const int crow = (reg & 3) + 8 * (reg >> 2) + 4 * hk;
            sb[crow * 65 + r]      = acc0[reg] * 0.0625f;
            sb[crow * 65 + 32 + r] = acc1[reg] * 0.0625f;
        }
        __syncthreads();

        // Running top-16 per row: lane r owns row r of its wave.
        if (lane < 32) {
            for (int i = 0; i < BN; ++i) {
                const float s = sb[r * 65 + i];
                const int idx = s0 + i;
                if (s > thr || (s == thr && idx < thr_id)) {
                    tk_sc[lbase + minslot] = s;
                    tk_id[lbase + minslot] = idx;
                    float nthr = 3.402823466e38f; int nid = (int)0x80000000, nslot = 0;
#pragma unroll
                    for (int j = 0; j < 16; ++j) {
                        const float ts = tk_sc[lbase + j];
                        const int ti = tk_id[lbase + j];
                        if (ts < nthr || (ts == nthr && ti > nid)) { nthr = ts; nid = ti; nslot = j; }
                    }
                    thr = nthr; thr_id = nid; minslot = nslot;
                }
            }
        }
    }
    __syncthreads();
    if (lane < 32) {
        const int grow = blockIdx.x * BM + wave * 32 + r;
        for (int j = 0; j < 16; ++j) {
            part_sc[(grow * NSPLIT + split) * TOPKK + j] = tk_sc[lbase + j];
            part_id[(grow * NSPLIT + split) * TOPKK + j] = tk_id[lbase + j];
        }
    }
}

// ---------------------------------------------------------------------------
// Merge partials -> global top-16 -> softmax -> weighted gather of v.
// One wave per ego row (4 rows/block), 2048 blocks.
// ---------------------------------------------------------------------------
__global__ __launch_bounds__(256) void merge_kernel(
    const float* __restrict__ part_sc, const int* __restrict__ part_id,
    const float* __restrict__ v, float* __restrict__ out)
{
    __shared__ float ssel[4][16];
    __shared__ int   isel[4][16];
    const int tid = threadIdx.x, lane = tid & 63, wave = tid >> 6;
    const int row = blockIdx.x * 4 + wave;

    float cs = part_sc[row * 64 + lane];
    int cid = part_id[row * 64 + lane];
    float m = 0.f;

    for (int t = 0; t < 16; ++t) {
        float bs = cs; int bid = cid;
#pragma unroll
        for (int o = 1; o < 64; o <<= 1) {
            const float os = __shfl_xor(bs, o);
            const int oid = __shfl_xor(bid, o);
            if (os > bs || (os == bs && oid < bid)) { bs = os; bid = oid; }
        }
        if (t == 0) m = bs;
        if (cid == bid) {                 // unique owner (ids are distinct)
            ssel[wave][t] = cs;
            isel[wave][t] = cid;
            cs = NEG_BIG; cid = 0x7fffffff;
        }
    }
    __syncthreads();

    float e[16]; float denom = 0.f;
#pragma unroll
    for (int t = 0; t < 16; ++t) { e[t] = expf(ssel[wave][t] - m); denom += e[t]; }
    const float inv = 1.0f / denom;

    float a0 = 0.f, a1 = 0.f, a2 = 0.f, a3 = 0.f;
    for (int t = 0; t < 16; ++t) {       // rank order == reference sum order
        const float w = e[t] * inv;
        const float* vp = v + (long)isel[wave][t] * EMB;
        a0 += w * vp[lane];
        a1 += w * vp[lane + 64];
        a2 += w * vp[lane + 128];
        a3 += w * vp[lane + 192];
    }
    out[row * EMB + lane]       = a0;
    out[row * EMB + lane + 64]  = a1;
    out[row * EMB + lane + 128] = a2;
    out[row * EMB + lane + 192] = a3;
}

// ---------------------------------------------------------------------------
extern "C" void kernel_launch(void* const* d_in, const int* in_sizes, int n_in,
                              void* d_out, int out_size, void* d_ws, size_t ws_size,
                              hipStream_t stream) {
    (void)in_sizes; (void)n_in; (void)out_size; (void)ws_size;
    const float* ego  = (const float*)d_in[0];
    const float* side = (const float*)d_in[1];
    const float* rel  = (const float*)d_in[2];
    const float* Wq   = (const float*)d_in[3];
    const float* bq   = (const float*)d_in[4];
    const float* Wk   = (const float*)d_in[5];
    const float* bk   = (const float*)d_in[6];
    const float* Wv   = (const float*)d_in[7];
    const float* bv   = (const float*)d_in[8];

    char* ws = (char*)d_ws;                      // ~28MB used
    _Float16* qh = (_Float16*)ws;                // 4MB each
    _Float16* ql = qh + (size_t)NEGO * EMB;
    _Float16* kh = ql + (size_t)NEGO * EMB;
    _Float16* kl = kh + (size_t)NEGO * EMB;
    float* vbuf    = (float*)(ws + 16u * 1024 * 1024);   // 8MB
    float* part_sc = (float*)(ws + 24u * 1024 * 1024);   // 2MB
    int*   part_id = (int*)  (ws + 26u * 1024 * 1024);   // 2MB
    float* out = (float*)d_out;

    proj_kernel<<<dim3(NEGO / BM, 3), dim3(256), 0, stream>>>(
        ego, side, rel, Wq, bq, Wk, bk, Wv, bv, qh, ql, kh, kl, vbuf);
    scores_topk_kernel<<<dim3(NEGO / BM, NSPLIT), dim3(256), 0, stream>>>(
        qh, ql, kh, kl, part_sc, part_id);
    merge_kernel<<<dim3(NEGO / 4), dim3(256), 0, stream>>>(
        part_sc, part_id, vbuf, out);
}

// Round 3
// 591.079 us; speedup vs baseline: 2.7515x; 2.7515x over previous
//
#include <hip/hip_runtime.h>
#include <hip/hip_bf16.h>

// ---------------------------------------------------------------------------
// SparseKnowledgeAttention: q=ego@Wq.T+bq; k=(side*rel)@Wk.T+bk; v=side@Wv.T+bv
// scores=q@k.T/16 -> top16/row -> softmax -> weighted gather of v.
// fp16x3 split-precision MFMA (f32-exact scores so selection matches the f32
// reference). Fused scores+top16: ballot-filter from accumulators against a
// per-row threshold, rare survivors drained into per-lane REGISTER top-16
// lists (lane wr owns row wr) -> all 32 rows processed in parallel.
// ---------------------------------------------------------------------------

#define EMB 256
#define NEGO 8192
#define NSIDE 8192
#define TOPKK 16
#define NSPLIT 4
#define SPLITLEN (NSIDE / NSPLIT)   // 2048
#define BM 128                      // ego rows per block (4 waves x 32)
#define BN 64                       // side cols per iteration

typedef _Float16 f16x8 __attribute__((ext_vector_type(8)));
typedef float f32x16 __attribute__((ext_vector_type(16)));

#define NEG_BIG (-3.402823466e38f)

__device__ __forceinline__ void gload_lds16(const _Float16* g, _Float16* l) {
    __builtin_amdgcn_global_load_lds((const __attribute__((address_space(1))) void*)g,
                                     (__attribute__((address_space(3))) void*)l, 16, 0, 0);
}

__device__ __forceinline__ void split8(const float* xv, f16x8& hi, f16x8& lo) {
#pragma unroll
    for (int j = 0; j < 8; ++j) {
        float x = xv[j];
        _Float16 h = (_Float16)x;
        hi[j] = h;
        lo[j] = (_Float16)(x - (float)h);
    }
}

// ---------------------------------------------------------------------------
// Projection kernel: C = X @ W.T + b  via fp16x3 MFMA. z = 0:q, 1:k, 2:v.
// grid (64, 3), block 256. Outputs: q,k as f16 hi/lo pairs; v as f32.
// ---------------------------------------------------------------------------
__global__ __launch_bounds__(256, 1) void proj_kernel(
    const float* __restrict__ ego, const float* __restrict__ side, const float* __restrict__ rel,
    const float* __restrict__ Wq, const float* __restrict__ bq,
    const float* __restrict__ Wk, const float* __restrict__ bk,
    const float* __restrict__ Wv, const float* __restrict__ bv,
    _Float16* __restrict__ qh, _Float16* __restrict__ ql,
    _Float16* __restrict__ kh, _Float16* __restrict__ kl,
    float* __restrict__ vout)
{
    __shared__ __align__(16) _Float16 Wh[64 * 256];   // 32KB, chunk-swizzled
    __shared__ __align__(16) _Float16 Wl[64 * 256];   // 32KB

    const int z = blockIdx.y;
    const float* X; const float* W; const float* bias;
    if (z == 0)      { X = ego;  W = Wq; bias = bq; }
    else if (z == 1) { X = side; W = Wk; bias = bk; }
    else             { X = side; W = Wv; bias = bv; }

    const int tid = threadIdx.x, lane = tid & 63, wave = tid >> 6;
    const int hk = lane >> 5, r = lane & 31;
    const int arow = blockIdx.x * BM + wave * 32 + r;

    // A fragments (rows of X), fp16 split, held in registers for whole block.
    f16x8 ah[16], al[16];
#pragma unroll
    for (int kst = 0; kst < 16; ++kst) {
        float xv[8];
        const float* p = X + arow * EMB + kst * 16 + hk * 8;
        const float4 x0 = *(const float4*)p;
        const float4 x1 = *(const float4*)(p + 4);
        xv[0]=x0.x; xv[1]=x0.y; xv[2]=x0.z; xv[3]=x0.w;
        xv[4]=x1.x; xv[5]=x1.y; xv[6]=x1.z; xv[7]=x1.w;
        if (z == 1) {
            const float* pr = rel + arow * EMB + kst * 16 + hk * 8;
            const float4 r0 = *(const float4*)pr;
            const float4 r1 = *(const float4*)(pr + 4);
            xv[0]*=r0.x; xv[1]*=r0.y; xv[2]*=r0.z; xv[3]*=r0.w;
            xv[4]*=r1.x; xv[5]*=r1.y; xv[6]*=r1.z; xv[7]*=r1.w;
        }
        split8(xv, ah[kst], al[kst]);
    }

    for (int nt = 0; nt < 4; ++nt) {
        __syncthreads();
        // Stage W rows [nt*64, nt*64+64) into LDS, split + chunk-swizzled.
#pragma unroll
        for (int i = 0; i < 8; ++i) {
            const int rowi = wave * 16 + i * 2 + hk;
            const int c = r;
            const float* wp = W + (nt * 64 + rowi) * EMB + ((c ^ (rowi & 31)) << 3);
            float xv[8];
            const float4 w0 = *(const float4*)wp;
            const float4 w1 = *(const float4*)(wp + 4);
            xv[0]=w0.x; xv[1]=w0.y; xv[2]=w0.z; xv[3]=w0.w;
            xv[4]=w1.x; xv[5]=w1.y; xv[6]=w1.z; xv[7]=w1.w;
            f16x8 h8, l8;
            split8(xv, h8, l8);
            *(f16x8*)&Wh[rowi * 256 + c * 8] = h8;
            *(f16x8*)&Wl[rowi * 256 + c * 8] = l8;
        }
        __syncthreads();

        f32x16 acc0 = {}, acc1 = {};
#pragma unroll
        for (int kst = 0; kst < 16; ++kst) {
            const int cc = kst * 2 + hk;
            const f16x8 bh0 = *(const f16x8*)&Wh[r * 256 + ((cc ^ r) << 3)];
            const f16x8 bl0 = *(const f16x8*)&Wl[r * 256 + ((cc ^ r) << 3)];
            const f16x8 bh1 = *(const f16x8*)&Wh[(32 + r) * 256 + ((cc ^ r) << 3)];
            const f16x8 bl1 = *(const f16x8*)&Wl[(32 + r) * 256 + ((cc ^ r) << 3)];
            acc0 = __builtin_amdgcn_mfma_f32_32x32x16_f16(ah[kst], bh0, acc0, 0, 0, 0);
            acc0 = __builtin_amdgcn_mfma_f32_32x32x16_f16(al[kst], bh0, acc0, 0, 0, 0);
            acc0 = __builtin_amdgcn_mfma_f32_32x32x16_f16(ah[kst], bl0, acc0, 0, 0, 0);
            acc1 = __builtin_amdgcn_mfma_f32_32x32x16_f16(ah[kst], bh1, acc1, 0, 0, 0);
            acc1 = __builtin_amdgcn_mfma_f32_32x32x16_f16(al[kst], bh1, acc1, 0, 0, 0);
            acc1 = __builtin_amdgcn_mfma_f32_32x32x16_f16(ah[kst], bl1, acc1, 0, 0, 0);
        }

        // Epilogue: add bias, write (split f16 for q/k; f32 for v).
#pragma unroll
        for (int reg = 0; reg < 16; ++reg) {
            const int crow = (reg & 3) + 8 * (reg >> 2) + 4 * hk;
            const int grow = blockIdx.x * BM + wave * 32 + crow;
            const int col0 = nt * 64 + r;
            const int col1 = nt * 64 + 32 + r;
            const float v0 = acc0[reg] + bias[col0];
            const float v1 = acc1[reg] + bias[col1];
            if (z < 2) {
                _Float16* oh = (z == 0) ? qh : kh;
                _Float16* ol = (z == 0) ? ql : kl;
                _Float16 h0 = (_Float16)v0;
                oh[grow * EMB + col0] = h0;
                ol[grow * EMB + col0] = (_Float16)(v0 - (float)h0);
                _Float16 h1 = (_Float16)v1;
                oh[grow * EMB + col1] = h1;
                ol[grow * EMB + col1] = (_Float16)(v1 - (float)h1);
            } else {
                vout[grow * EMB + col0] = v0;
                vout[grow * EMB + col1] = v1;
            }
        }
    }
}

// ---------------------------------------------------------------------------
// Fused scores + top-16. grid (64, NSPLIT), block 256 (4 waves x 32 rows).
// Ballot-filter from accumulators vs per-row threshold; survivors drained into
// per-lane register top-16 lists (lane wr owns local row wr of its wave).
// All filter/drain LDS state is per-wave-owned -> no barriers in that phase.
// ---------------------------------------------------------------------------
__global__ __launch_bounds__(256, 1) void scores_topk_kernel(
    const _Float16* __restrict__ qh, const _Float16* __restrict__ ql,
    const _Float16* __restrict__ kh, const _Float16* __restrict__ kl,
    float* __restrict__ part_sc, int* __restrict__ part_id)
{
    __shared__ __align__(16) _Float16 Bh[BN * 256];     // 32KB swizzled k-tile (hi)
    __shared__ __align__(16) _Float16 Bl[BN * 256];     // 32KB (lo)
    __shared__ float          rbS[4 * 32 * 65];         // 33.3KB survivor scores
    __shared__ unsigned short rbC[4 * 32 * 66];         // 16.9KB survivor cols
    __shared__ float Tsh[4 * 32];                       // per-row running threshold
    __shared__ int   cntsh[4 * 32];

    const int tid = threadIdx.x, lane = tid & 63, wave = tid >> 6;
    const int hk = lane >> 5, r = lane & 31;
    const int split = blockIdx.y;
    const int myrow = lane & 31;                        // owner-lane local row
    const int rbase = wave * 32 + myrow;

    for (int i = tid; i < 4 * 32; i += 256) { Tsh[i] = NEG_BIG; cntsh[i] = 0; }

    // Per-lane register top-16 list for row `myrow` of this wave.
    float tkS[16]; int tkI[16];
#pragma unroll
    for (int j = 0; j < 16; ++j) { tkS[j] = NEG_BIG; tkI[j] = 0x7fffffff; }
    float curmin = NEG_BIG; int curminslot = 0;

    // Q fragments in registers for the whole side loop.
    const int qrow = blockIdx.x * BM + wave * 32 + r;
    f16x8 ah[16], al[16];
#pragma unroll
    for (int kst = 0; kst < 16; ++kst) {
        ah[kst] = *(const f16x8*)(qh + qrow * EMB + kst * 16 + hk * 8);
        al[kst] = *(const f16x8*)(ql + qrow * EMB + kst * 16 + hk * 8);
    }
    __syncthreads();   // Tsh/cntsh init visible

    for (int it = 0; it < SPLITLEN / BN; ++it) {
        const int s0 = split * SPLITLEN + it * BN;
        // Stage k-tile hi/lo (source pre-swizzled so the linear LDS dest
        // realizes chunk ^= (row&31) -> low-conflict ds_read_b128).
#pragma unroll
        for (int i = 0; i < 8; ++i) {
            const int rowi = wave * 16 + i * 2 + hk;
            const int c = r;
            const int gsrc = (s0 + rowi) * EMB + ((c ^ (rowi & 31)) << 3);
            gload_lds16(kh + gsrc, &Bh[(wave * 16 + i * 2) * 256]);
            gload_lds16(kl + gsrc, &Bl[(wave * 16 + i * 2) * 256]);
        }
        __syncthreads();   // staged (compiler drains vmcnt before barrier)

        f32x16 acc0 = {}, acc1 = {};
#pragma unroll
        for (int kst = 0; kst < 16; ++kst) {
            const int cc = kst * 2 + hk;
            const f16x8 bh0 = *(const f16x8*)&Bh[r * 256 + ((cc ^ r) << 3)];
            const f16x8 bl0 = *(const f16x8*)&Bl[r * 256 + ((cc ^ r) << 3)];
            const f16x8 bh1 = *(const f16x8*)&Bh[(32 + r) * 256 + ((cc ^ r) << 3)];
            const f16x8 bl1 = *(const f16x8*)&Bl[(32 + r) * 256 + ((cc ^ r) << 3)];
            acc0 = __builtin_amdgcn_mfma_f32_32x32x16_f16(ah[kst], bh0, acc0, 0, 0, 0);
            acc0 = __builtin_amdgcn_mfma_f32_32x32x16_f16(al[kst], bh0, acc0, 0, 0, 0);
            acc0 = __builtin_amdgcn_mfma_f32_32x32x16_f16(ah[kst], bl0, acc0, 0, 0, 0);
            acc1 = __builtin_amdgcn_mfma_f32_32x32x16_f16(ah[kst], bh1, acc1, 0, 0, 0);
            acc1 = __builtin_amdgcn_mfma_f32_32x32x16_f16(al[kst], bh1, acc1, 0, 0, 0);
            acc1 = __builtin_amdgcn_mfma_f32_32x32x16_f16(ah[kst], bl1, acc1, 0, 0, 0);
        }

        // ---- filter + drain (no barriers: all LDS state is per-wave) ----
#pragma unroll
        for (int g = 0; g < 4; ++g) {
#pragma unroll
            for (int q4 = 0; q4 < 4; ++q4) {
                const int reg = g * 4 + q4;
                const int row = (reg & 3) + 8 * (reg >> 2) + 4 * hk;   // local row
                const int tb = wave * 32 + row;
                // acc0 candidate: col r
                {
                    const float v = acc0[reg] * 0.0625f;
                    const float T = Tsh[tb];
                    const bool p = v > T;
                    const unsigned long long m = __ballot(p);
                    const unsigned gm = (unsigned)(hk ? (m >> 32) : m);
                    if (p) {
                        const int ofs = __popc(gm & ((1u << r) - 1));
                        const int base = cntsh[tb];
                        rbS[tb * 65 + base + ofs] = v;
                        rbC[tb * 66 + base + ofs] = (unsigned short)r;
                        if (ofs == 0) cntsh[tb] = base + __popc(gm);
                    }
                }
                // acc1 candidate: col 32+r
                {
                    const float v = acc1[reg] * 0.0625f;
                    const float T = Tsh[tb];
                    const bool p = v > T;
                    const unsigned long long m = __ballot(p);
                    const unsigned gm = (unsigned)(hk ? (m >> 32) : m);
                    if (p) {
                        const int ofs = __popc(gm & ((1u << r) - 1));
                        const int base = cntsh[tb];
                        rbS[tb * 65 + base + ofs] = v;
                        rbC[tb * 66 + base + ofs] = (unsigned short)(32 + r);
                        if (ofs == 0) cntsh[tb] = base + __popc(gm);
                    }
                }
            }
            // Drain: lane wr processes row wr's survivors into its register list.
            {
                const int cnt = (lane < 32) ? cntsh[rbase] : 0;
                for (int e = 0; e < cnt; ++e) {
                    const float s = rbS[rbase * 65 + e];
                    const int c = rbC[rbase * 66 + e];
                    if (s > curmin) {
                        const int idx = s0 + c;
#pragma unroll
                        for (int j = 0; j < 16; ++j) {
                            const bool sel = (j == curminslot);
                            tkS[j] = sel ? s : tkS[j];
                            tkI[j] = sel ? idx : tkI[j];
                        }
                        float mn = tkS[0]; int ms = 0;
#pragma unroll
                        for (int j = 1; j < 16; ++j) {
                            const bool sel = tkS[j] < mn;
                            mn = sel ? tkS[j] : mn;
                            ms = sel ? j : ms;
                        }
                        curmin = mn; curminslot = ms;
                    }
                }
                if (lane < 32 && cnt > 0) { Tsh[rbase] = curmin; cntsh[rbase] = 0; }
            }
        }
        __syncthreads();   // everyone done reading Bh/Bl before next stage
    }

    if (lane < 32) {
        const int grow = blockIdx.x * BM + wave * 32 + myrow;
#pragma unroll
        for (int j = 0; j < 16; ++j) {
            part_sc[(grow * NSPLIT + split) * TOPKK + j] = tkS[j];
            part_id[(grow * NSPLIT + split) * TOPKK + j] = tkI[j];
        }
    }
}

// ---------------------------------------------------------------------------
// Merge partials -> global top-16 -> softmax -> weighted gather of v.
// One wave per ego row (4 rows/block), 2048 blocks.
// ---------------------------------------------------------------------------
__global__ __launch_bounds__(256) void merge_kernel(
    const float* __restrict__ part_sc, const int* __restrict__ part_id,
    const float* __restrict__ v, float* __restrict__ out)
{
    __shared__ float ssel[4][16];
    __shared__ int   isel[4][16];
    const int tid = threadIdx.x, lane = tid & 63, wave = tid >> 6;
    const int row = blockIdx.x * 4 + wave;

    float cs = part_sc[row * 64 + lane];
    int cid = part_id[row * 64 + lane];
    float m = 0.f;

    for (int t = 0; t < 16; ++t) {
        float bs = cs; int bid = cid;
#pragma unroll
        for (int o = 1; o < 64; o <<= 1) {
            const float os = __shfl_xor(bs, o);
            const int oid = __shfl_xor(bid, o);
            if (os > bs || (os == bs && oid < bid)) { bs = os; bid = oid; }
        }
        if (t == 0) m = bs;
        if (cid == bid) {                 // unique owner (ids are distinct)
            ssel[wave][t] = cs;
            isel[wave][t] = cid;
            cs = NEG_BIG; cid = 0x7fffffff;
        }
    }
    __syncthreads();

    float e[16]; float denom = 0.f;
#pragma unroll
    for (int t = 0; t < 16; ++t) { e[t] = expf(ssel[wave][t] - m); denom += e[t]; }
    const float inv = 1.0f / denom;

    float a0 = 0.f, a1 = 0.f, a2 = 0.f, a3 = 0.f;
    for (int t = 0; t < 16; ++t) {       // rank order == reference sum order
        const float w = e[t] * inv;
        const float* vp = v + (long)isel[wave][t] * EMB;
        a0 += w * vp[lane];
        a1 += w * vp[lane + 64];
        a2 += w * vp[lane + 128];
        a3 += w * vp[lane + 192];
    }
    out[row * EMB + lane]       = a0;
    out[row * EMB + lane + 64]  = a1;
    out[row * EMB + lane + 128] = a2;
    out[row * EMB + lane + 192] = a3;
}

// ---------------------------------------------------------------------------
extern "C" void kernel_launch(void* const* d_in, const int* in_sizes, int n_in,
                              void* d_out, int out_size, void* d_ws, size_t ws_size,
                              hipStream_t stream) {
    (void)in_sizes; (void)n_in; (void)out_size; (void)ws_size;
    const float* ego  = (const float*)d_in[0];
    const float* side = (const float*)d_in[1];
    const float* rel  = (const float*)d_in[2];
    const float* Wq   = (const float*)d_in[3];
    const float* bq   = (const float*)d_in[4];
    const float* Wk   = (const float*)d_in[5];
    const float* bk   = (const float*)d_in[6];
    const float* Wv   = (const float*)d_in[7];
    const float* bv   = (const float*)d_in[8];

    char* ws = (char*)d_ws;                      // ~28MB used
    _Float16* qh = (_Float16*)ws;                // 4MB each
    _Float16* ql = qh + (size_t)NEGO * EMB;
    _Float16* kh = ql + (size_t)NEGO * EMB;
    _Float16* kl = kh + (size_t)NEGO * EMB;
    float* vbuf    = (float*)(ws + 16u * 1024 * 1024);   // 8MB
    float* part_sc = (float*)(ws + 24u * 1024 * 1024);   // 2MB
    int*   part_id = (int*)  (ws + 26u * 1024 * 1024);   // 2MB
    float* out = (float*)d_out;

    proj_kernel<<<dim3(NEGO / BM, 3), dim3(256), 0, stream>>>(
        ego, side, rel, Wq, bq, Wk, bk, Wv, bv, qh, ql, kh, kl, vbuf);
    scores_topk_kernel<<<dim3(NEGO / BM, NSPLIT), dim3(256), 0, stream>>>(
        qh, ql, kh, kl, part_sc, part_id);
    merge_kernel<<<dim3(NEGO / 4), dim3(256), 0, stream>>>(
        part_sc, part_id, vbuf, out);
}

// Round 4
// 260.173 us; speedup vs baseline: 6.2510x; 2.2719x over previous
//
#include <hip/hip_runtime.h>
#include <hip/hip_bf16.h>

// ---------------------------------------------------------------------------
// SparseKnowledgeAttention: q=ego@Wq.T+bq; k=(side*rel)@Wk.T+bk; v=side@Wv.T+bv
// scores=q@k.T/16 -> top16/row -> softmax -> weighted gather of v.
// fp16x3 split-precision MFMA (f32-exact scores). Swapped-operand MFMA
// (S^T = K·Q^T) makes each ego-row's candidates lane-local; selection via
// branchless filter-to-LDS-stack + batched rebuild into register top-16.
// ---------------------------------------------------------------------------

#define EMB 256
#define NEGO 8192
#define NSIDE 8192
#define TOPKK 16
#define NSPLIT 4
#define SPLITLEN (NSIDE / NSPLIT)   // 2048
#define BM 128                      // ego rows per block (4 waves x 32)
#define BN 64                       // side rows per iteration
#define CAP 32                      // stack capacity (alloc 33: unconditional-write slop)

typedef _Float16 f16x8 __attribute__((ext_vector_type(8)));
typedef float f32x16 __attribute__((ext_vector_type(16)));

#define NEG_BIG (-3.402823466e38f)

__device__ __forceinline__ void gload_lds16(const _Float16* g, _Float16* l) {
    __builtin_amdgcn_global_load_lds((const __attribute__((address_space(1))) void*)g,
                                     (__attribute__((address_space(3))) void*)l, 16, 0, 0);
}

__device__ __forceinline__ void split8(const float* xv, f16x8& hi, f16x8& lo) {
#pragma unroll
    for (int j = 0; j < 8; ++j) {
        float x = xv[j];
        _Float16 h = (_Float16)x;
        hi[j] = h;
        lo[j] = (_Float16)(x - (float)h);
    }
}

// ---------------------------------------------------------------------------
// Projection kernel: C = X @ W.T + b  via fp16x3 MFMA. z = 0:q, 1:k, 2:v.
// grid (64, 3), block 256. Outputs: q,k as f16 hi/lo pairs; v as f32.
// ---------------------------------------------------------------------------
__global__ __launch_bounds__(256, 1) void proj_kernel(
    const float* __restrict__ ego, const float* __restrict__ side, const float* __restrict__ rel,
    const float* __restrict__ Wq, const float* __restrict__ bq,
    const float* __restrict__ Wk, const float* __restrict__ bk,
    const float* __restrict__ Wv, const float* __restrict__ bv,
    _Float16* __restrict__ qh, _Float16* __restrict__ ql,
    _Float16* __restrict__ kh, _Float16* __restrict__ kl,
    float* __restrict__ vout)
{
    __shared__ __align__(16) _Float16 Wh[64 * 256];   // 32KB, chunk-swizzled
    __shared__ __align__(16) _Float16 Wl[64 * 256];   // 32KB

    const int z = blockIdx.y;
    const float* X; const float* W; const float* bias;
    if (z == 0)      { X = ego;  W = Wq; bias = bq; }
    else if (z == 1) { X = side; W = Wk; bias = bk; }
    else             { X = side; W = Wv; bias = bv; }

    const int tid = threadIdx.x, lane = tid & 63, wave = tid >> 6;
    const int hk = lane >> 5, r = lane & 31;
    const int arow = blockIdx.x * BM + wave * 32 + r;

    f16x8 ah[16], al[16];
#pragma unroll
    for (int kst = 0; kst < 16; ++kst) {
        float xv[8];
        const float* p = X + arow * EMB + kst * 16 + hk * 8;
        const float4 x0 = *(const float4*)p;
        const float4 x1 = *(const float4*)(p + 4);
        xv[0]=x0.x; xv[1]=x0.y; xv[2]=x0.z; xv[3]=x0.w;
        xv[4]=x1.x; xv[5]=x1.y; xv[6]=x1.z; xv[7]=x1.w;
        if (z == 1) {
            const float* pr = rel + arow * EMB + kst * 16 + hk * 8;
            const float4 r0 = *(const float4*)pr;
            const float4 r1 = *(const float4*)(pr + 4);
            xv[0]*=r0.x; xv[1]*=r0.y; xv[2]*=r0.z; xv[3]*=r0.w;
            xv[4]*=r1.x; xv[5]*=r1.y; xv[6]*=r1.z; xv[7]*=r1.w;
        }
        split8(xv, ah[kst], al[kst]);
    }

    for (int nt = 0; nt < 4; ++nt) {
        __syncthreads();
#pragma unroll
        for (int i = 0; i < 8; ++i) {
            const int rowi = wave * 16 + i * 2 + hk;
            const int c = r;
            const float* wp = W + (nt * 64 + rowi) * EMB + ((c ^ (rowi & 31)) << 3);
            float xv[8];
            const float4 w0 = *(const float4*)wp;
            const float4 w1 = *(const float4*)(wp + 4);
            xv[0]=w0.x; xv[1]=w0.y; xv[2]=w0.z; xv[3]=w0.w;
            xv[4]=w1.x; xv[5]=w1.y; xv[6]=w1.z; xv[7]=w1.w;
            f16x8 h8, l8;
            split8(xv, h8, l8);
            *(f16x8*)&Wh[rowi * 256 + c * 8] = h8;
            *(f16x8*)&Wl[rowi * 256 + c * 8] = l8;
        }
        __syncthreads();

        f32x16 acc0 = {}, acc1 = {};
#pragma unroll
        for (int kst = 0; kst < 16; ++kst) {
            const int cc = kst * 2 + hk;
            const f16x8 bh0 = *(const f16x8*)&Wh[r * 256 + ((cc ^ r) << 3)];
            const f16x8 bl0 = *(const f16x8*)&Wl[r * 256 + ((cc ^ r) << 3)];
            const f16x8 bh1 = *(const f16x8*)&Wh[(32 + r) * 256 + ((cc ^ r) << 3)];
            const f16x8 bl1 = *(const f16x8*)&Wl[(32 + r) * 256 + ((cc ^ r) << 3)];
            acc0 = __builtin_amdgcn_mfma_f32_32x32x16_f16(ah[kst], bh0, acc0, 0, 0, 0);
            acc0 = __builtin_amdgcn_mfma_f32_32x32x16_f16(al[kst], bh0, acc0, 0, 0, 0);
            acc0 = __builtin_amdgcn_mfma_f32_32x32x16_f16(ah[kst], bl0, acc0, 0, 0, 0);
            acc1 = __builtin_amdgcn_mfma_f32_32x32x16_f16(ah[kst], bh1, acc1, 0, 0, 0);
            acc1 = __builtin_amdgcn_mfma_f32_32x32x16_f16(al[kst], bh1, acc1, 0, 0, 0);
            acc1 = __builtin_amdgcn_mfma_f32_32x32x16_f16(ah[kst], bl1, acc1, 0, 0, 0);
        }

#pragma unroll
        for (int reg = 0; reg < 16; ++reg) {
            const int crow = (reg & 3) + 8 * (reg >> 2) + 4 * hk;
            const int grow = blockIdx.x * BM + wave * 32 + crow;
            const int col0 = nt * 64 + r;
            const int col1 = nt * 64 + 32 + r;
            const float v0 = acc0[reg] + bias[col0];
            const float v1 = acc1[reg] + bias[col1];
            if (z < 2) {
                _Float16* oh = (z == 0) ? qh : kh;
                _Float16* ol = (z == 0) ? ql : kl;
                _Float16 h0 = (_Float16)v0;
                oh[grow * EMB + col0] = h0;
                ol[grow * EMB + col0] = (_Float16)(v0 - (float)h0);
                _Float16 h1 = (_Float16)v1;
                oh[grow * EMB + col1] = h1;
                ol[grow * EMB + col1] = (_Float16)(v1 - (float)h1);
            } else {
                vout[grow * EMB + col0] = v0;
                vout[grow * EMB + col1] = v1;
            }
        }
    }
}

// ---------------------------------------------------------------------------
// Fused scores + top-16, swapped operands: acc = K_tile · Q^T, so lane r of
// each wave holds all scores of ego-row (qbase+r) for its hk-half of side
// rows. Per-lane register top-16 + LDS survivor stack + batched rebuilds.
// grid (64, NSPLIT), block 256 (4 waves x 32 ego rows each).
// ---------------------------------------------------------------------------
__global__ __launch_bounds__(256, 1) void scores_topk_kernel(
    const _Float16* __restrict__ qh, const _Float16* __restrict__ ql,
    const _Float16* __restrict__ kh, const _Float16* __restrict__ kl,
    float* __restrict__ part_sc, int* __restrict__ part_id)
{
    __shared__ __align__(16) _Float16 Bh[BN * 256];        // 32KB swizzled k-tile (hi)
    __shared__ __align__(16) _Float16 Bl[BN * 256];        // 32KB (lo)
    __shared__ unsigned long long stk[(CAP + 1) * 256];    // 66KB survivor stacks

    const int tid = threadIdx.x, lane = tid & 63, wave = tid >> 6;
    const int hk = lane >> 5, r = lane & 31;
    const int split = blockIdx.y;
    const int qbase = blockIdx.x * BM + wave * 32;
    const int rowoff0 = 4 * hk;

    // Per-lane register top-16 (distinct sentinels: value-keyed replace-min).
    float tkS[16]; int tkC[16];
#pragma unroll
    for (int j = 0; j < 16; ++j) { tkS[j] = -3.0e38f - (float)j * 1.0e30f; tkC[j] = 0x7fffffff; }
    float curmin = NEG_BIG;
    int cnt = 0;

    // Q fragments (row qbase+r) in registers — also the exact B-operand layout.
    f16x8 ah[16], al[16];
#pragma unroll
    for (int kst = 0; kst < 16; ++kst) {
        ah[kst] = *(const f16x8*)(qh + (qbase + r) * EMB + kst * 16 + hk * 8);
        al[kst] = *(const f16x8*)(ql + (qbase + r) * EMB + kst * 16 + hk * 8);
    }

    auto rebuild = [&]() {
        for (int e = 0; e < CAP; ++e) {
            if (!__any(e < cnt)) break;
            const unsigned long long v = stk[e * 256 + tid];
            float s = __uint_as_float((unsigned)(v & 0xffffffffu));
            const int col = (int)(v >> 32);
            s = (e < cnt) ? s : NEG_BIG;            // mask garbage lanes
            const bool p = s > curmin;
            const float cmkey = p ? curmin : 3.0e38f;  // never matches when !p
#pragma unroll
            for (int j = 0; j < 16; ++j) {
                const bool hit = (tkS[j] == cmkey);
                tkS[j] = hit ? s : tkS[j];
                tkC[j] = hit ? col : tkC[j];
            }
            float m0 = fminf(tkS[0], tkS[1]),  m1 = fminf(tkS[2], tkS[3]);
            float m2 = fminf(tkS[4], tkS[5]),  m3 = fminf(tkS[6], tkS[7]);
            float m4 = fminf(tkS[8], tkS[9]),  m5 = fminf(tkS[10], tkS[11]);
            float m6 = fminf(tkS[12], tkS[13]), m7 = fminf(tkS[14], tkS[15]);
            m0 = fminf(m0, m1); m2 = fminf(m2, m3); m4 = fminf(m4, m5); m6 = fminf(m6, m7);
            curmin = fminf(fminf(m0, m2), fminf(m4, m6));
        }
        cnt = 0;
    };

    for (int it = 0; it < SPLITLEN / BN; ++it) {
        // Stage k-tile hi/lo (pre-swizzled source -> linear LDS dest realizes
        // chunk ^= (row&31); conflict-free ds_read_b128).
#pragma unroll
        for (int i = 0; i < 8; ++i) {
            const int rowi = wave * 16 + i * 2 + hk;
            const int c = r;
            const int gsrc = (split * SPLITLEN + it * BN + rowi) * EMB + ((c ^ (rowi & 31)) << 3);
            gload_lds16(kh + gsrc, &Bh[(wave * 16 + i * 2) * 256]);
            gload_lds16(kl + gsrc, &Bl[(wave * 16 + i * 2) * 256]);
        }
        __syncthreads();   // staged (compiler drains vmcnt before barrier)

#pragma unroll
        for (int sg = 0; sg < 2; ++sg) {
            f32x16 acc = {};
#pragma unroll
            for (int kst = 0; kst < 16; ++kst) {
                const int slice = kst * 2 + hk;
                const int addr = (sg * 32 + r) * 256 + ((slice ^ r) << 3);
                const f16x8 kh_f = *(const f16x8*)&Bh[addr];
                const f16x8 kl_f = *(const f16x8*)&Bl[addr];
                acc = __builtin_amdgcn_mfma_f32_32x32x16_f16(kh_f, ah[kst], acc, 0, 0, 0);
                acc = __builtin_amdgcn_mfma_f32_32x32x16_f16(kl_f, ah[kst], acc, 0, 0, 0);
                acc = __builtin_amdgcn_mfma_f32_32x32x16_f16(kh_f, al[kst], acc, 0, 0, 0);
            }

            if (it == 0 && sg == 0) {
                // Fill: first 16 candidates initialize the list directly.
#pragma unroll
                for (int j = 0; j < 16; ++j) {
                    tkS[j] = acc[j] * 0.0625f;
                    tkC[j] = (j & 3) + 8 * (j >> 2) + rowoff0;
                }
                float m0 = fminf(tkS[0], tkS[1]),  m1 = fminf(tkS[2], tkS[3]);
                float m2 = fminf(tkS[4], tkS[5]),  m3 = fminf(tkS[6], tkS[7]);
                float m4 = fminf(tkS[8], tkS[9]),  m5 = fminf(tkS[10], tkS[11]);
                float m6 = fminf(tkS[12], tkS[13]), m7 = fminf(tkS[14], tkS[15]);
                m0 = fminf(m0, m1); m2 = fminf(m2, m3); m4 = fminf(m4, m5); m6 = fminf(m6, m7);
                curmin = fminf(fminf(m0, m2), fminf(m4, m6));
            } else {
                const int base_col = it * BN + sg * 32 + rowoff0;
                // Branchless filter to per-thread stack (entry-major: conflict-free).
#pragma unroll
                for (int j = 0; j < 16; ++j) {
                    const float s = acc[j] * 0.0625f;
                    const int col = base_col + (j & 3) + 8 * (j >> 2);
                    const bool p = s > curmin;
                    const unsigned long long ev =
                        ((unsigned long long)(unsigned)col << 32) | (unsigned long long)__float_as_uint(s);
                    stk[cnt * 256 + tid] = ev;      // unconditional; slop slot CAP
                    cnt += p ? 1 : 0;
                }
                if (__any(cnt > 16)) rebuild();
            }
        }
        __syncthreads();   // all waves done reading Bh/Bl before restage
    }
    rebuild();             // drain residue

    const int row = qbase + r;
#pragma unroll
    for (int j = 0; j < 16; ++j) {
        const int o = ((row * NSPLIT + split) * 2 + hk) * TOPKK + j;
        part_sc[o] = tkS[j];
        part_id[o] = (tkC[j] == 0x7fffffff) ? 0x7fffffff
                                            : split * SPLITLEN + tkC[j];
    }
}

// ---------------------------------------------------------------------------
// Merge 128 partials/row -> global top-16 -> softmax -> weighted gather of v.
// One wave per ego row (4 rows/block), 2048 blocks.
// ---------------------------------------------------------------------------
__global__ __launch_bounds__(256) void merge_kernel(
    const float* __restrict__ part_sc, const int* __restrict__ part_id,
    const float* __restrict__ v, float* __restrict__ out)
{
    __shared__ float ssel[4][16];
    __shared__ int   isel[4][16];
    const int tid = threadIdx.x, lane = tid & 63, wave = tid >> 6;
    const int row = blockIdx.x * 4 + wave;

    float c0 = part_sc[row * 128 + lane];
    float c1 = part_sc[row * 128 + 64 + lane];
    int   i0 = part_id[row * 128 + lane];
    int   i1 = part_id[row * 128 + 64 + lane];
    float m = 0.f;

    for (int t = 0; t < 16; ++t) {
        const bool sel1 = (c1 > c0) || (c1 == c0 && i1 < i0);
        float bs = sel1 ? c1 : c0;
        int   bid = sel1 ? i1 : i0;
#pragma unroll
        for (int o = 1; o < 64; o <<= 1) {
            const float os = __shfl_xor(bs, o);
            const int oid = __shfl_xor(bid, o);
            if (os > bs || (os == bs && oid < bid)) { bs = os; bid = oid; }
        }
        if (t == 0) m = bs;
        if (lane == 0) { ssel[wave][t] = bs; isel[wave][t] = bid; }
        if (i0 == bid) c0 = NEG_BIG;
        if (i1 == bid) c1 = NEG_BIG;
    }
    __syncthreads();

    float e[16]; float denom = 0.f;
#pragma unroll
    for (int t = 0; t < 16; ++t) { e[t] = expf(ssel[wave][t] - m); denom += e[t]; }
    const float inv = 1.0f / denom;

    float a0 = 0.f, a1 = 0.f, a2 = 0.f, a3 = 0.f;
    for (int t = 0; t < 16; ++t) {       // rank order == reference sum order
        const float w = e[t] * inv;
        const float* vp = v + (long)isel[wave][t] * EMB;
        a0 += w * vp[lane];
        a1 += w * vp[lane + 64];
        a2 += w * vp[lane + 128];
        a3 += w * vp[lane + 192];
    }
    out[row * EMB + lane]       = a0;
    out[row * EMB + lane + 64]  = a1;
    out[row * EMB + lane + 128] = a2;
    out[row * EMB + lane + 192] = a3;
}

// ---------------------------------------------------------------------------
extern "C" void kernel_launch(void* const* d_in, const int* in_sizes, int n_in,
                              void* d_out, int out_size, void* d_ws, size_t ws_size,
                              hipStream_t stream) {
    (void)in_sizes; (void)n_in; (void)out_size; (void)ws_size;
    const float* ego  = (const float*)d_in[0];
    const float* side = (const float*)d_in[1];
    const float* rel  = (const float*)d_in[2];
    const float* Wq   = (const float*)d_in[3];
    const float* bq   = (const float*)d_in[4];
    const float* Wk   = (const float*)d_in[5];
    const float* bk   = (const float*)d_in[6];
    const float* Wv   = (const float*)d_in[7];
    const float* bv   = (const float*)d_in[8];

    char* ws = (char*)d_ws;                      // 32MB used
    _Float16* qh = (_Float16*)ws;                // 4MB each
    _Float16* ql = qh + (size_t)NEGO * EMB;
    _Float16* kh = ql + (size_t)NEGO * EMB;
    _Float16* kl = kh + (size_t)NEGO * EMB;
    float* vbuf    = (float*)(ws + 16u * 1024 * 1024);   // 8MB
    float* part_sc = (float*)(ws + 24u * 1024 * 1024);   // 4MB
    int*   part_id = (int*)  (ws + 28u * 1024 * 1024);   // 4MB
    float* out = (float*)d_out;

    proj_kernel<<<dim3(NEGO / BM, 3), dim3(256), 0, stream>>>(
        ego, side, rel, Wq, bq, Wk, bk, Wv, bv, qh, ql, kh, kl, vbuf);
    scores_topk_kernel<<<dim3(NEGO / BM, NSPLIT), dim3(256), 0, stream>>>(
        qh, ql, kh, kl, part_sc, part_id);
    merge_kernel<<<dim3(NEGO / 4), dim3(256), 0, stream>>>(
        part_sc, part_id, vbuf, out);
}